// Round 6
// baseline (198.361 us; speedup 1.0000x reference)
//
#include <hip/hip_runtime.h>
#include <stdint.h>

// RelScaleAttend: b=4, 16 heads, s=1024 (32x32 img), d=64. TWO kernels:
//
// K1 repack: K,V f32 [b,s,16,64] -> bf16 tiles in d_ws, 8 KB contiguous per
//   (head, ktile): Kp[bh][kt][row r][dim c] and Vp[bh][kt][dim d][key kk]
//   (V transposed via LDS), both with the flash kernel's LDS XOR swizzle
//   (byte ^= (row&7)<<4) PRE-BAKED into the stored layout. This removes the
//   4KB-strided 256B row-gather pattern from the hot kernel entirely -- the
//   one invariant across rounds 0-5, all of which pinned at ~130us with every
//   pipe <30% busy (time tracked neither phases, nor work, nor residency).
//
// K2 attn: block = (h-pair, bh), 64 queries, 4 waves. Per 64-key tile the
//   staging is 4 global_load_lds_dwordx4 of SEQUENTIAL packed bytes (no VALU
//   cvt, no ds_write, no prefetch registers); double-buffered, one
//   vmcnt(0)+s_barrier per tile. Compute identical to R5: swapped-operand
//   QK^T (lane holds full query rows; softmax per-lane; PV A-fragment =
//   lane's own p values), STATIC-max softmax (exact), XCD head-affinity
//   swizzle. LDS = RelH 8KB + arena 32KB = 40960 -> 4 blocks/CU.
//   Numerics identical to R0-R5 (same bf16 rounding, same MFMA order).

#define SCALE2 0.18033688f   // 0.125 * log2(e)
#define LOG2E  1.44269504f

typedef float  f32x4  __attribute__((ext_vector_type(4)));
typedef __bf16 bf16x8 __attribute__((ext_vector_type(8)));
typedef __bf16 bf16x4 __attribute__((ext_vector_type(4)));

#define AS1 __attribute__((address_space(1)))
#define AS3 __attribute__((address_space(3)))

__device__ inline bf16x8 pack8(f32x4 a, f32x4 b) {
    bf16x8 t;
    t[0]=(__bf16)a.x; t[1]=(__bf16)a.y; t[2]=(__bf16)a.z; t[3]=(__bf16)a.w;
    t[4]=(__bf16)b.x; t[5]=(__bf16)b.y; t[6]=(__bf16)b.z; t[7]=(__bf16)b.w;
    return t;
}

// ---------------- kernel 1: repack ----------------
__global__ __launch_bounds__(256) void repack(
        const float* __restrict__ kg, const float* __restrict__ vg,
        char* __restrict__ kp, char* __restrict__ vp) {
    __shared__ float Vt[64 * 68];          // f32 transpose buffer (16B-aligned rows)
    const int t   = threadIdx.x;
    const int idx = blockIdx.x;            // 1024 = 64 bh x 16 kt
    const int bh  = idx >> 4, kt = idx & 15;
    const int bb  = bh >> 4, nh = bh & 15;
    const int inbase = bb * 1048576 + nh * 64;
    char* kout = kp + bh * 131072 + kt * 8192;
    char* vout = vp + bh * 131072 + kt * 8192;

    const int r  = t >> 2;                 // 0..63 (row / dim)
    const int c0 = (t & 3) << 4;           // 0,16,32,48

    // ---- K: row r, 16 dims -> swizzled bf16 ----
    {
        const float* src = kg + inbase + (kt * 64 + r) * 1024 + c0;
        f32x4 a = ((const f32x4*)src)[0], b = ((const f32x4*)src)[1];
        f32x4 c = ((const f32x4*)src)[2], d = ((const f32x4*)src)[3];
        const int swz = (r & 7) << 4;
        *(bf16x8*)(kout + r * 128 + ((c0 * 2) ^ swz))      = pack8(a, b);
        *(bf16x8*)(kout + r * 128 + ((c0 * 2 + 16) ^ swz)) = pack8(c, d);
    }
    // ---- V: rows -> LDS, transpose, [dim][key] swizzled bf16 ----
    {
        const float* src = vg + inbase + (kt * 64 + r) * 1024 + c0;
        f32x4 a = ((const f32x4*)src)[0], b = ((const f32x4*)src)[1];
        f32x4 c = ((const f32x4*)src)[2], d = ((const f32x4*)src)[3];
        float* dst = &Vt[r * 68 + c0];
        ((f32x4*)dst)[0] = a; ((f32x4*)dst)[1] = b;
        ((f32x4*)dst)[2] = c; ((f32x4*)dst)[3] = d;
    }
    __syncthreads();
    {
        const int d0  = r;                 // output dim row
        const int kk0 = c0;                // 16 keys
        float x[16];
#pragma unroll
        for (int j = 0; j < 16; ++j) x[j] = Vt[(kk0 + j) * 68 + d0];
        f32x4 a = {x[0], x[1], x[2], x[3]},   b = {x[4], x[5], x[6], x[7]};
        f32x4 c = {x[8], x[9], x[10], x[11]}, d = {x[12], x[13], x[14], x[15]};
        const int swz = (d0 & 7) << 4;
        *(bf16x8*)(vout + d0 * 128 + ((kk0 * 2) ^ swz))      = pack8(a, b);
        *(bf16x8*)(vout + d0 * 128 + ((kk0 * 2 + 16) ^ swz)) = pack8(c, d);
    }
}

// ---------------- kernel 2: attention ----------------
__global__ __launch_bounds__(256, 3) void attn(
        const float* __restrict__ qg,
        const char* __restrict__ kp, const char* __restrict__ vp,
        const float* __restrict__ rph, const float* __restrict__ rpw,
        float* __restrict__ outg) {
    __shared__ float RelH[64 * 32];               // 8192 B, swizzled 128-B rows
    __shared__ __align__(16) char arena[32768];
    float* Ql   = (float*)arena;                  // phase0 [0,17408)
    float* RelW = (float*)(arena + 17408);        // phase0 [17408,26112), stride 34
    float* MH   = (float*)(arena + 26112);        // phase0 [26112,27136)
    // phase1: buf b at arena + b*16384: K tile 8 KB | V tile 8 KB (packed images)

    const int tid  = threadIdx.x;
    const int w    = tid >> 6, lane = tid & 63;
    const int quad = lane >> 4, n16 = lane & 15;
    const int sw16 = (n16 & 7) << 4;              // read-side row swizzle

    // ---- XCD head-affinity swizzle ----
    const int idx = blockIdx.x;
    const int xc  = idx & 7;
    const int r_  = idx >> 3;
    const int hp  = r_ & 15;
    const int bh  = xc + ((r_ >> 4) << 3);

    const int bb = bh >> 4, nh = bh & 15;
    const int h0 = hp << 1;
    const int base = bb * 1048576 + nh * 64;      // per-head f32 element base
    const int sq0  = h0 * 32;                     // first query row of block
    const char* kpb = kp + bh * 131072;           // packed K for this head
    const char* vpb = vp + bh * 131072;           // packed V for this head

    // ---- stage Q rows (fp32) into LDS, coalesced b128 ----
    {
        int r0 = tid >> 4, c0 = (tid & 15) << 2;
#pragma unroll
        for (int k = 0; k < 4; ++k) {
            int row = k * 16 + r0;
            f32x4 v = *(const f32x4*)(qg + base + (sq0 + row) * 1024 + c0);
            *(f32x4*)&Ql[row * 68 + c0] = v;
        }
    }
    __syncthreads();

    // ---- phase 0: rel tables (x log2e) + per-slot max ----
    {
        int ql = tid & 63, slot = tid >> 6;
        int isw = slot >> 1, khb = (slot & 1) << 4;
        int hh = h0 + (ql >> 5), wl = ql & 31;
        int row0 = (isw ? wl : hh) + 31 - khb;      // row_j = row0 - j
        const float* tp = (isw ? rpw : rph) + row0 * 64;
        const float* qrow = &Ql[ql * 68];
        float acc[16];
#pragma unroll
        for (int j = 0; j < 16; ++j) acc[j] = 0.f;
#pragma unroll 4
        for (int cq = 0; cq < 16; ++cq) {
            f32x4 qv = *(const f32x4*)(qrow + cq * 4);
#pragma unroll
            for (int j = 0; j < 16; ++j) {
                f32x4 tv = *(const f32x4*)(tp - j * 64 + cq * 4);
                acc[j] += qv.x * tv.x + qv.y * tv.y + qv.z * tv.z + qv.w * tv.w;
            }
        }
        float hmax = -1e30f;
        if (isw) {
            float* dst = RelW + ql * 34 + khb;
#pragma unroll
            for (int j = 0; j < 16; ++j) {
                float v = acc[j] * LOG2E;
                dst[j] = v;
                hmax = fmaxf(hmax, v);
            }
        } else {
            char* rowH = (char*)RelH + ql * 128;
            int swz = (ql & 7) << 4;
#pragma unroll
            for (int j = 0; j < 16; ++j) {
                float v = acc[j] * LOG2E;
                *(float*)(rowH + ((((khb + j) << 2)) ^ swz)) = v;
                hmax = fmaxf(hmax, v);
            }
        }
        MH[slot * 64 + ql] = hmax;
    }

    // ---- Q fragments (MFMA B-operand): lane holds Q[w*16+n16][quad*8+j]
    const int qn = w * 16 + n16;             // this lane's softmax query
    bf16x8 qf[2];
#pragma unroll
    for (int ch = 0; ch < 2; ++ch) {
        const float* qp = &Ql[qn * 68 + ch * 32 + quad * 8];
        f32x4 a = ((const f32x4*)qp)[0];
        f32x4 b = ((const f32x4*)qp)[1];
        qf[ch] = pack8(a, b);
    }
    __syncthreads();   // phase-0 writes visible; all waves' Ql reads done

    // ---- per-lane static max M and rwm2[i][r] = RelW[qn][i*16+quad*4+r] - M
    float rwm2[2][4];
    {
        float M = fmaxf(MH[qn], MH[64 + qn]) + fmaxf(MH[128 + qn], MH[192 + qn]);
#pragma unroll
        for (int i = 0; i < 2; ++i) {
            float2 u  = *(const float2*)&RelW[qn * 34 + i * 16 + quad * 4];
            float2 v2 = *(const float2*)&RelW[qn * 34 + i * 16 + quad * 4 + 2];
            rwm2[i][0] = u.x - M;  rwm2[i][1] = u.y - M;
            rwm2[i][2] = v2.x - M; rwm2[i][3] = v2.y - M;
        }
    }
    // rwm reads are consumed (lgkm-waited) before the first loop barrier;
    // buf1 (which aliases RelW/MH) is first written by gl_lds AFTER it.

    float lr = 0.f;
    f32x4 oc[4];
#pragma unroll
    for (int i = 0; i < 4; ++i) oc[i] = (f32x4){0.f, 0.f, 0.f, 0.f};

    // ---- async staging: 4 x global_load_lds_dwordx4 per thread per tile ----
    // wave w stages K bytes [w*2K, w*2K+2K) and V bytes likewise; LDS dst is
    // wave-uniform base (+ lane*16 implicit); global src is per-lane.
    const int lo16 = lane * 16;
    auto GLDS = [&](int buf, int kt) {
        const char* ks = kpb + kt * 8192 + w * 2048 + lo16;
        const char* vs = vpb + kt * 8192 + w * 2048 + lo16;
        char* ld = arena + buf * 16384 + w * 2048;
        __builtin_amdgcn_global_load_lds((const AS1 void*)ks,
                                         (AS3 void*)ld,          16, 0, 0);
        __builtin_amdgcn_global_load_lds((const AS1 void*)(ks + 1024),
                                         (AS3 void*)(ld + 1024), 16, 0, 0);
        __builtin_amdgcn_global_load_lds((const AS1 void*)vs,
                                         (AS3 void*)(ld + 8192), 16, 0, 0);
        __builtin_amdgcn_global_load_lds((const AS1 void*)(vs + 1024),
                                         (AS3 void*)(ld + 9216), 16, 0, 0);
    };

    // prologue: tile 0 -> buf0 (overlaps Ql, dead after the syncthreads above)
    GLDS(0, 0);

    for (int kt = 0; kt < 16; ++kt) {
        // my gl_lds done (vmcnt counts them; no other VMEM in the loop),
        // then barrier => everyone's staging of buf[kt&1] is visible.
        asm volatile("s_waitcnt vmcnt(0)" ::: "memory");
        __builtin_amdgcn_s_barrier();

        // issue next tile into the other buffer (its readers all crossed the
        // barrier above); lands during this tile's compute.
        if (kt < 15) GLDS((kt + 1) & 1, kt + 1);

        const char* kbase = arena + (kt & 1) * 16384;
        const char* vbase = kbase + 8192;

        // ---- S^T = K Q^T : 8 MFMAs; s[g][r] = S[key=g*16+quad*4+r][qn] ----
        f32x4 s[4];
#pragma unroll
        for (int g = 0; g < 4; ++g) s[g] = (f32x4){0.f, 0.f, 0.f, 0.f};
#pragma unroll
        for (int ch = 0; ch < 2; ++ch)
#pragma unroll
            for (int g = 0; g < 4; ++g) {
                bf16x8 kf = *(const bf16x8*)(kbase + (g * 16 + n16) * 128
                                             + ((ch * 64 + quad * 16) ^ sw16));
                s[g] = __builtin_amdgcn_mfma_f32_16x16x32_bf16(kf, qf[ch], s[g], 0, 0, 0);
            }

        // ---- static-max softmax, per-lane: kh=kt*2+(g>>1), kw=(g&1)*16+quad*4+r
        float2 rhp = *(const float2*)((const char*)RelH + qn * 128 + ((kt * 8) ^ sw16));
        float p[4][4];
#pragma unroll
        for (int g = 0; g < 4; ++g) {
            const float rbase = (g >= 2) ? rhp.y : rhp.x;
#pragma unroll
            for (int r = 0; r < 4; ++r)
                p[g][r] = __builtin_amdgcn_exp2f(fmaf(s[g][r], SCALE2, rbase + rwm2[g & 1][r]));
        }
#pragma unroll
        for (int g = 0; g < 4; ++g)
            lr += ((p[g][0] + p[g][1]) + (p[g][2] + p[g][3]));

        // ---- PV A-fragments: lane's own p values (zero shuffle) ----
        bf16x8 pf[2];
#pragma unroll
        for (int ko = 0; ko < 2; ++ko) {
            bf16x8 t;
            t[0] = (__bf16)p[2 * ko][0];     t[1] = (__bf16)p[2 * ko][1];
            t[2] = (__bf16)p[2 * ko][2];     t[3] = (__bf16)p[2 * ko][3];
            t[4] = (__bf16)p[2 * ko + 1][0]; t[5] = (__bf16)p[2 * ko + 1][1];
            t[6] = (__bf16)p[2 * ko + 1][2]; t[7] = (__bf16)p[2 * ko + 1][3];
            pf[ko] = t;
        }

        // ---- O += P V : B-fragment from packed [dim][key] swizzled V tile ----
#pragma unroll
        for (int ko = 0; ko < 2; ++ko)
#pragma unroll
            for (int cn = 0; cn < 4; ++cn) {
                const char* vb = vbase + (cn * 16 + n16) * 128;
                bf16x4 a = *(const bf16x4*)(vb + ((ko * 64 + quad * 8) ^ sw16));
                bf16x4 b = *(const bf16x4*)(vb + ((ko * 64 + quad * 8 + 32) ^ sw16));
                bf16x8 vf;
                vf[0] = a[0]; vf[1] = a[1]; vf[2] = a[2]; vf[3] = a[3];
                vf[4] = b[0]; vf[5] = b[1]; vf[6] = b[2]; vf[7] = b[3];
                oc[cn] = __builtin_amdgcn_mfma_f32_16x16x32_bf16(pf[ko], vf, oc[cn], 0, 0, 0);
            }
    }

    // ---- epilogue: full row-sum per query, redistribute, store ----
    lr += __shfl_xor(lr, 16);
    lr += __shfl_xor(lr, 32);
    float linv[4];
#pragma unroll
    for (int r = 0; r < 4; ++r)
        linv[r] = 1.f / __shfl(lr, quad * 4 + r, 64);   // L[query = quad*4+r]

    // oc[cn][r] = O[query = w*16 + quad*4 + r][dim = cn*16 + n16]
#pragma unroll
    for (int r = 0; r < 4; ++r) {
        int ob = base + (sq0 + w * 16 + quad * 4 + r) * 1024 + n16;
        outg[ob]      = oc[0][r] * linv[r];
        outg[ob + 16] = oc[1][r] * linv[r];
        outg[ob + 32] = oc[2][r] * linv[r];
        outg[ob + 48] = oc[3][r] * linv[r];
    }
}

extern "C" void kernel_launch(void* const* d_in, const int* in_sizes, int n_in,
                              void* d_out, int out_size, void* d_ws, size_t ws_size,
                              hipStream_t stream) {
    (void)in_sizes; (void)n_in; (void)out_size; (void)ws_size;
    const float* q   = (const float*)d_in[0];
    const float* k   = (const float*)d_in[1];
    const float* v   = (const float*)d_in[2];
    const float* rph = (const float*)d_in[3];
    const float* rpw = (const float*)d_in[4];
    char* kp = (char*)d_ws;                 // 8 MB packed K
    char* vp = kp + 8388608;                // 8 MB packed V
    repack<<<dim3(1024), 256, 0, stream>>>(k, v, kp, vp);
    attn<<<dim3(1024), 256, 0, stream>>>(q, kp, vp, rph, rpw, (float*)d_out);
}